// Round 14
// baseline (222.458 us; speedup 1.0000x reference)
//
#include <hip/hip_runtime.h>
#include <hip/hip_fp8.h>

#define N_NODES 50000
#define N_EDGES 800000
#define NBUCK 196       // ceil(50000/256) buckets of 256 nodes
#define PBLK 391        // ceil(800000/2048) partition blocks
#define CAP 5120        // bucket window capacity

typedef unsigned short ushort_t;
typedef unsigned char uchar_t;
typedef short short8 __attribute__((ext_vector_type(8)));
typedef float floatx4 __attribute__((ext_vector_type(4)));

__device__ __forceinline__ float bf2f(ushort_t u) {
    unsigned v = ((unsigned)u) << 16;
    return __builtin_bit_cast(float, v);
}
__device__ __forceinline__ ushort_t f2bf(float f) {
    unsigned u = __builtin_bit_cast(unsigned, f);
    unsigned r = (u + 0x7FFFu + ((u >> 16) & 1u)) >> 16;  // RNE
    return (ushort_t)r;
}
__device__ __forceinline__ uchar_t f2fp8(float f) {
    __hip_fp8_e4m3 t(f);
    return (uchar_t)t.__x;
}
__device__ __forceinline__ float fp82f(uchar_t u) {
    __hip_fp8_e4m3 t;
    t.__x = (__hip_fp8_storage_t)u;
    return (float)t;
}
__device__ __forceinline__ float4 ld4(const float* p) { return *(const float4*)p; }

// ---------------- prep: cvt_x (bf16 + fp8) + cvt_w + bucket cursor init ----------------
__global__ __launch_bounds__(256) void prep_kernel(
    const float* __restrict__ x,
    const float* __restrict__ W1_rel, const float* __restrict__ W1_root,
    const float* __restrict__ W2_rel, const float* __restrict__ W2_root,
    const float* __restrict__ Wmu_rel, const float* __restrict__ Wls_rel,
    const float* __restrict__ Wmu_root, const float* __restrict__ Wls_root,
    ushort_t* __restrict__ ax, uchar_t* __restrict__ xq,
    ushort_t* __restrict__ B1t, ushort_t* __restrict__ B2t, ushort_t* __restrict__ B3t,
    int* __restrict__ bcursor) {
    int idx = blockIdx.x * blockDim.x + threadIdx.x;
    if (idx < 400000) {                       // ax[n,64:128] = bf16(x); xq[n,:] = fp8(x)
        int n = idx >> 3, c = (idx & 7) * 8;
        float4 v0 = ld4(x + (size_t)n * 64 + c);
        float4 v1 = ld4(x + (size_t)n * 64 + c + 4);
        float vv[8] = {v0.x, v0.y, v0.z, v0.w, v1.x, v1.y, v1.z, v1.w};
        short8 o;
        unsigned q0 = 0, q1 = 0;
        #pragma unroll
        for (int i = 0; i < 4; ++i) {
            o[i] = f2bf(vv[i]);
            o[4 + i] = f2bf(vv[4 + i]);
            q0 |= ((unsigned)f2fp8(vv[i])) << (8 * i);
            q1 |= ((unsigned)f2fp8(vv[4 + i])) << (8 * i);
        }
        *(short8*)(ax + (size_t)n * 128 + 64 + c) = o;
        uint2 q = {q0, q1};
        *(uint2*)(xq + (size_t)n * 64 + c) = q;
    } else if (idx < 506496) {                // transposed bf16 weights
        int j = idx - 400000;
        if (j < 32768) {
            int n = j >> 7, k = j & 127;
            float v = (k < 64) ? W1_rel[k * 256 + n] : W1_root[(k - 64) * 256 + n];
            B1t[j] = f2bf(v);
        } else if (j < 98304) {
            int jj = j - 32768;
            int n = jj >> 8, k = jj & 255;
            float v = (n < 128) ? W2_rel[k * 128 + n] : W2_root[k * 128 + (n - 128)];
            B2t[jj] = f2bf(v);
        } else {
            int jj = j - 98304;
            int n = jj >> 7, k = jj & 127;
            const float* W = (n < 16) ? Wmu_rel : (n < 32) ? Wls_rel : (n < 48) ? Wmu_root : Wls_root;
            B3t[jj] = f2bf(W[k * 16 + (n & 15)]);
        }
    } else if (idx < 506496 + NBUCK) {
        int b = idx - 506496;
        bcursor[b] = b * CAP;
    }
}

// ---------------- single-pass partition into fixed bucket windows ----------------
__global__ __launch_bounds__(256) void partition_kernel(
    const int* __restrict__ src, const int* __restrict__ dst,
    int* __restrict__ bcursor, unsigned* __restrict__ pairbuf) {
    __shared__ int h[NBUCK];
    __shared__ int cur[NBUCK];
    const int tid = threadIdx.x;
    for (int i = tid; i < NBUCK; i += 256) h[i] = 0;
    __syncthreads();
    const int base = blockIdx.x * 2048;
    int d[8];
    #pragma unroll
    for (int j = 0; j < 8; ++j) {
        int e = base + j * 256 + tid;
        if (e < N_EDGES) { d[j] = dst[e]; atomicAdd(&h[d[j] >> 8], 1); }
        else d[j] = -1;
    }
    __syncthreads();
    for (int i = tid; i < NBUCK; i += 256) {
        int c = h[i];
        cur[i] = c ? atomicAdd(&bcursor[i], c) : 0;
    }
    __syncthreads();
    #pragma unroll
    for (int j = 0; j < 8; ++j) {
        int e = base + j * 256 + tid;
        if (e < N_EDGES) {
            int dd = d[j];
            int slot = atomicAdd(&cur[dd >> 8], 1);
            pairbuf[slot] = (unsigned)src[e] | ((unsigned)(dd & 255) << 16);
        }
    }
}

// per-bucket: node histogram + scan -> row_beg/row_end/dinv; LDS-cursor fill of 16-bit eidx
__global__ __launch_bounds__(256) void fill_bucket_kernel(
    const unsigned* __restrict__ pairbuf, const int* __restrict__ bcursor,
    int* __restrict__ row_beg, int* __restrict__ row_end,
    float* __restrict__ dinv, ushort_t* __restrict__ eidx) {
    __shared__ int h[256];
    __shared__ int sm[256];
    __shared__ int cur[256];
    const int b = blockIdx.x, tid = threadIdx.x;
    const int beg = b * CAP, end = bcursor[b];
    h[tid] = 0;
    __syncthreads();
    for (int i = beg + tid; i < end; i += 256)
        atomicAdd(&h[pairbuf[i] >> 16], 1);
    __syncthreads();
    int c = h[tid];
    sm[tid] = c;
    __syncthreads();
    #pragma unroll
    for (int off = 1; off < 256; off <<= 1) {
        int t = (tid >= off) ? sm[tid - off] : 0;
        __syncthreads();
        sm[tid] += t;
        __syncthreads();
    }
    int exc = beg + sm[tid] - c;
    int node = b * 256 + tid;
    if (node < N_NODES) {
        row_beg[node] = exc;
        row_end[node] = exc + c;
        dinv[node] = c > 0 ? 1.0f / (float)c : 0.0f;
    }
    cur[tid] = exc;
    __syncthreads();
    for (int i = beg + tid; i < end; i += 256) {
        unsigned v = pairbuf[i];
        int slot = atomicAdd(&cur[v >> 16], 1);
        eidx[slot] = (ushort_t)(v & 0xFFFFu);
    }
}

// ---------------- gather 1: ax[:, 0:64] = mean-gather of xq (fp8) ----------------
__global__ __launch_bounds__(256) void gather1_kernel(
    const int* __restrict__ row_beg, const int* __restrict__ row_end,
    const ushort_t* __restrict__ eidx, const float* __restrict__ dinv,
    const uchar_t* __restrict__ xq, ushort_t* __restrict__ ax) {
    const int lane = threadIdx.x & 7;
    const int nl = threadIdx.x >> 3;
    const int n = blockIdx.x * 32 + nl;
    if (n >= N_NODES) return;
    const int beg = row_beg[n], end = row_end[n];
    float a0[8] = {}, a1[8] = {}, a2[8] = {}, a3[8] = {};
    int j = beg;
    for (; j + 3 < end; j += 4) {
        uint2 v0 = *(const uint2*)(xq + (size_t)eidx[j] * 64 + lane * 8);
        uint2 v1 = *(const uint2*)(xq + (size_t)eidx[j + 1] * 64 + lane * 8);
        uint2 v2 = *(const uint2*)(xq + (size_t)eidx[j + 2] * 64 + lane * 8);
        uint2 v3 = *(const uint2*)(xq + (size_t)eidx[j + 3] * 64 + lane * 8);
        #pragma unroll
        for (int i = 0; i < 4; ++i) {
            a0[i]     += fp82f((uchar_t)(v0.x >> (8 * i)));
            a0[4 + i] += fp82f((uchar_t)(v0.y >> (8 * i)));
            a1[i]     += fp82f((uchar_t)(v1.x >> (8 * i)));
            a1[4 + i] += fp82f((uchar_t)(v1.y >> (8 * i)));
            a2[i]     += fp82f((uchar_t)(v2.x >> (8 * i)));
            a2[4 + i] += fp82f((uchar_t)(v2.y >> (8 * i)));
            a3[i]     += fp82f((uchar_t)(v3.x >> (8 * i)));
            a3[4 + i] += fp82f((uchar_t)(v3.y >> (8 * i)));
        }
    }
    for (; j < end; ++j) {
        uint2 v0 = *(const uint2*)(xq + (size_t)eidx[j] * 64 + lane * 8);
        #pragma unroll
        for (int i = 0; i < 4; ++i) {
            a0[i]     += fp82f((uchar_t)(v0.x >> (8 * i)));
            a0[4 + i] += fp82f((uchar_t)(v0.y >> (8 * i)));
        }
    }
    float d = dinv[n];
    short8 o;
    #pragma unroll
    for (int i = 0; i < 8; ++i) o[i] = f2bf(((a0[i] + a1[i]) + (a2[i] + a3[i])) * d);
    *(short8*)(ax + (size_t)n * 128 + lane * 8) = o;
}

// ---------------- fused gemm1+gemm2 (LDS-staged B both phases, h1 lives in LDS) ----------------
// Phase 1: H = relu(ax @ B1t + b1) in LDS (64 x 256 bf16, pitch 268).
// Phase 2: [t2 fp8 | r2 bf16] = H @ B2t, B2t staged in 32-row half-tiles.
__global__ __launch_bounds__(256) void g12_kernel(
    const ushort_t* __restrict__ ax, const ushort_t* __restrict__ B1t,
    const ushort_t* __restrict__ B2t, const float* __restrict__ b1,
    uchar_t* __restrict__ t2, ushort_t* __restrict__ r2) {
    constexpr int HP = 268;              // h1 row pitch (256 + 12 -> quad bank offset 6)
    __shared__ ushort_t H[64 * HP];      // 34,304 B
    __shared__ ushort_t Bs[8704];        // 17,408 B (phase1: 64x136; phase2: 32x264)
    const int tid = threadIdx.x;
    const int w = tid >> 6, lane = tid & 63;
    const int ln = lane & 15, quad = lane >> 4;
    const int rowbase = blockIdx.x * 64 + w * 16;
    int r = rowbase + ln; if (r > N_NODES - 1) r = N_NODES - 1;
    const int r0 = rowbase + quad * 4;

    // ---- phase 1: K=128, N=256, ny loop; D -> LDS H ----
    {
        short8 a1[4];
        #pragma unroll
        for (int s = 0; s < 4; ++s)
            a1[s] = *(const short8*)(ax + (size_t)r * 128 + s * 32 + quad * 8);
        for (int ny = 0; ny < 4; ++ny) {
            __syncthreads();
            for (int i = tid; i < 64 * 16; i += 256) {
                int row = i >> 4, off = (i & 15) * 8;
                *(short8*)(Bs + row * 136 + off) =
                    *(const short8*)(B1t + (size_t)(ny * 64 + row) * 128 + off);
            }
            __syncthreads();
            floatx4 acc[4] = {};
            #pragma unroll
            for (int f = 0; f < 4; ++f) {
                const ushort_t* bp = Bs + (f * 16 + ln) * 136 + quad * 8;
                #pragma unroll
                for (int s = 0; s < 4; ++s) {
                    short8 b = *(const short8*)(bp + s * 32);
                    acc[f] = __builtin_amdgcn_mfma_f32_16x16x32_bf16(a1[s], b, acc[f], 0, 0, 0);
                }
            }
            #pragma unroll
            for (int f = 0; f < 4; ++f) {
                int n = ny * 64 + f * 16 + ln;
                float bias = b1[n];
                #pragma unroll
                for (int g = 0; g < 4; ++g)
                    H[(w * 16 + quad * 4 + g) * HP + n] = f2bf(fmaxf(acc[f][g] + bias, 0.0f));
            }
        }
    }
    __syncthreads();   // H complete; Bs free
    // ---- phase 2: K=256, N=256 in 8 half-tiles of 32 cols ----
    short8 a2[8];
    #pragma unroll
    for (int s = 0; s < 8; ++s)
        a2[s] = *(const short8*)(H + (w * 16 + ln) * HP + s * 32 + quad * 8);
    for (int t = 0; t < 8; ++t) {
        if (t) __syncthreads();
        for (int i = tid; i < 32 * 32; i += 256) {
            int row = i >> 5, off = (i & 31) * 8;
            *(short8*)(Bs + row * 264 + off) =
                *(const short8*)(B2t + (size_t)(t * 32 + row) * 256 + off);
        }
        __syncthreads();
        floatx4 acc[2] = {};
        #pragma unroll
        for (int f = 0; f < 2; ++f) {
            const ushort_t* bp = Bs + (f * 16 + ln) * 264 + quad * 8;
            #pragma unroll
            for (int s = 0; s < 8; ++s) {
                short8 b = *(const short8*)(bp + s * 32);
                acc[f] = __builtin_amdgcn_mfma_f32_16x16x32_bf16(a2[s], b, acc[f], 0, 0, 0);
            }
        }
        #pragma unroll
        for (int f = 0; f < 2; ++f) {
            int n = t * 32 + f * 16 + ln;
            #pragma unroll
            for (int g = 0; g < 4; ++g) {
                int rr = r0 + g;
                if (rr >= N_NODES) continue;
                float v = acc[f][g];
                if (n < 128) t2[(size_t)rr * 128 + n] = f2fp8(v);
                else r2[(size_t)rr * 128 + (n - 128)] = f2bf(v);
            }
        }
    }
}

// ---------------- fused gather2 + combine + gemm3 (16 nodes/block, 16 threads/node) ----------------
__global__ __launch_bounds__(256) void g2g3_kernel(
    const uchar_t* __restrict__ t2, const ushort_t* __restrict__ r2,
    const int* __restrict__ row_beg, const int* __restrict__ row_end,
    const ushort_t* __restrict__ eidx, const float* __restrict__ dinv,
    const float* __restrict__ b2, const ushort_t* __restrict__ B3t,
    ushort_t* __restrict__ tml, float* __restrict__ rml) {
    constexpr int KP = 136;
    __shared__ ushort_t As[16 * KP];
    const int tid = threadIdx.x;
    const int nb = blockIdx.x * 16;   // 3125*16 = 50000 exact
    {
        const int nl = tid >> 4, lane = tid & 15;
        const int node = nb + nl;
        const int beg = row_beg[node], end = row_end[node];
        float a0[8] = {}, a1[8] = {}, a2[8] = {}, a3[8] = {};
        int j = beg;
        for (; j + 3 < end; j += 4) {
            uint2 v0 = *(const uint2*)(t2 + (size_t)eidx[j] * 128 + lane * 8);
            uint2 v1 = *(const uint2*)(t2 + (size_t)eidx[j + 1] * 128 + lane * 8);
            uint2 v2 = *(const uint2*)(t2 + (size_t)eidx[j + 2] * 128 + lane * 8);
            uint2 v3 = *(const uint2*)(t2 + (size_t)eidx[j + 3] * 128 + lane * 8);
            #pragma unroll
            for (int i = 0; i < 4; ++i) {
                a0[i]     += fp82f((uchar_t)(v0.x >> (8 * i)));
                a0[4 + i] += fp82f((uchar_t)(v0.y >> (8 * i)));
                a1[i]     += fp82f((uchar_t)(v1.x >> (8 * i)));
                a1[4 + i] += fp82f((uchar_t)(v1.y >> (8 * i)));
                a2[i]     += fp82f((uchar_t)(v2.x >> (8 * i)));
                a2[4 + i] += fp82f((uchar_t)(v2.y >> (8 * i)));
                a3[i]     += fp82f((uchar_t)(v3.x >> (8 * i)));
                a3[4 + i] += fp82f((uchar_t)(v3.y >> (8 * i)));
            }
        }
        for (; j < end; ++j) {
            uint2 v0 = *(const uint2*)(t2 + (size_t)eidx[j] * 128 + lane * 8);
            #pragma unroll
            for (int i = 0; i < 4; ++i) {
                a0[i]     += fp82f((uchar_t)(v0.x >> (8 * i)));
                a0[4 + i] += fp82f((uchar_t)(v0.y >> (8 * i)));
            }
        }
        float d = dinv[node];
        short8 rv = *(const short8*)(r2 + (size_t)node * 128 + lane * 8);
        float4 ba = ld4(b2 + lane * 8), bb = ld4(b2 + lane * 8 + 4);
        float bc[8] = {ba.x, ba.y, ba.z, ba.w, bb.x, bb.y, bb.z, bb.w};
        short8 o;
        #pragma unroll
        for (int i = 0; i < 8; ++i)
            o[i] = f2bf(fmaxf(((a0[i] + a1[i]) + (a2[i] + a3[i])) * d + bf2f((ushort_t)rv[i]) + bc[i], 0.0f));
        *(short8*)(As + nl * KP + lane * 8) = o;
    }
    __syncthreads();
    const int w = tid >> 6, lane64 = tid & 63;
    const int ln = lane64 & 15, quad = lane64 >> 4;
    short8 a[4];
    #pragma unroll
    for (int s = 0; s < 4; ++s)
        a[s] = *(const short8*)(As + ln * KP + s * 32 + quad * 8);
    floatx4 acc = {};
    const ushort_t* bp = B3t + (size_t)(w * 16 + ln) * 128 + quad * 8;
    #pragma unroll
    for (int s = 0; s < 4; ++s) {
        short8 b = *(const short8*)(bp + s * 32);
        acc = __builtin_amdgcn_mfma_f32_16x16x32_bf16(a[s], b, acc, 0, 0, 0);
    }
    const int r0 = nb + quad * 4;
    const int ncol = w * 16 + ln;
    #pragma unroll
    for (int g = 0; g < 4; ++g) {
        int rr = r0 + g;
        float v = acc[g];
        if (ncol < 32) tml[(size_t)rr * 32 + ncol] = f2bf(v);
        else rml[(size_t)rr * 32 + (ncol - 32)] = v;
    }
}

// ---------------- gather 3 (fused combine + split write) ----------------
__global__ __launch_bounds__(256) void gather3_kernel(
    const ushort_t* __restrict__ tml, const float* __restrict__ rml,
    const int* __restrict__ row_beg, const int* __restrict__ row_end,
    const ushort_t* __restrict__ eidx, const float* __restrict__ dinv,
    const float* __restrict__ bmu, const float* __restrict__ bls,
    float* __restrict__ out) {
    const int lane = threadIdx.x & 3;
    const int nl = threadIdx.x >> 2;
    const int n = blockIdx.x * 64 + nl;
    if (n >= N_NODES) return;
    const int beg = row_beg[n], end = row_end[n];
    float a0[8] = {}, a1[8] = {};
    int j = beg;
    for (; j + 1 < end; j += 2) {
        int s0 = eidx[j], s1 = eidx[j + 1];
        short8 v0 = *(const short8*)(tml + (size_t)s0 * 32 + lane * 8);
        short8 v1 = *(const short8*)(tml + (size_t)s1 * 32 + lane * 8);
        #pragma unroll
        for (int i = 0; i < 8; ++i) { a0[i] += bf2f((ushort_t)v0[i]); a1[i] += bf2f((ushort_t)v1[i]); }
    }
    if (j < end) {
        int s0 = eidx[j];
        short8 v0 = *(const short8*)(tml + (size_t)s0 * 32 + lane * 8);
        #pragma unroll
        for (int i = 0; i < 8; ++i) a0[i] += bf2f((ushort_t)v0[i]);
    }
    float d = dinv[n];
    const float* bias = (lane < 2) ? (bmu + lane * 8) : (bls + (lane - 2) * 8);
    float4 ra = ld4(rml + (size_t)n * 32 + lane * 8);
    float4 rb = ld4(rml + (size_t)n * 32 + lane * 8 + 4);
    float4 ba = ld4(bias);
    float4 bb = ld4(bias + 4);
    float rr[8] = {ra.x, ra.y, ra.z, ra.w, rb.x, rb.y, rb.z, rb.w};
    float bc[8] = {ba.x, ba.y, ba.z, ba.w, bb.x, bb.y, bb.z, bb.w};
    float res[8];
    #pragma unroll
    for (int i = 0; i < 8; ++i) res[i] = (a0[i] + a1[i]) * d + rr[i] + bc[i];
    float* base = (lane < 2) ? (out + (size_t)n * 16 + lane * 8)
                             : (out + 800000u + (size_t)n * 16 + (lane - 2) * 8);
    *(float4*)(base) = make_float4(res[0], res[1], res[2], res[3]);
    *(float4*)(base + 4) = make_float4(res[4], res[5], res[6], res[7]);
}

extern "C" void kernel_launch(void* const* d_in, const int* in_sizes, int n_in,
                              void* d_out, int out_size, void* d_ws, size_t ws_size,
                              hipStream_t stream) {
    const float* x       = (const float*)d_in[0];
    const float* W1_rel  = (const float*)d_in[1];
    const float* b1      = (const float*)d_in[2];
    const float* W1_root = (const float*)d_in[3];
    const float* W2_rel  = (const float*)d_in[4];
    const float* b2      = (const float*)d_in[5];
    const float* W2_root = (const float*)d_in[6];
    const float* Wmu_rel = (const float*)d_in[7];
    const float* bmu     = (const float*)d_in[8];
    const float* Wmu_root= (const float*)d_in[9];
    const float* Wls_rel = (const float*)d_in[10];
    const float* bls     = (const float*)d_in[11];
    const float* Wls_root= (const float*)d_in[12];
    const int*   ei      = (const int*)d_in[13];
    const int* src = ei;
    const int* dst = ei + N_EDGES;

    // ---- workspace layout ----
    int*      bcursor = (int*)d_ws;                      //       256
    int*      row_beg = bcursor + 256;                   //    50,048
    int*      row_end = row_beg + 50048;                 //    50,048
    unsigned* pairbuf = (unsigned*)(row_end + 50048);    // 1,003,520
    ushort_t* eidx    = (ushort_t*)(pairbuf + 1003520);  // 1,003,520 ush
    float*    dinv    = (float*)(eidx + 1003520);        //    50,000
    ushort_t* ax   = (ushort_t*)(dinv + 50000);          //  6,400,000  [N,128]: [agg | x]
    uchar_t*  t2   = (uchar_t*)(ax + 6400000);           //  6,400,000 B [N,128] fp8
    uchar_t*  xq   = t2 + 6400000;                       //  3,200,000 B [N,64] fp8
    ushort_t* r2   = (ushort_t*)(xq + 3200000);          //  6,400,000  [N,128] bf16
    ushort_t* tml  = r2 + 6400000;                       //  1,600,000  [N,32]  bf16
    ushort_t* B1t  = tml + 1600000;                      //     32,768
    ushort_t* B2t  = B1t + 32768;                        //     65,536
    ushort_t* B3t  = B2t + 65536;                        //      8,192
    float* rml     = (float*)(B3t + 8192);               //  1,600,000  [N,32] f32
    float* out     = (float*)d_out;

    // ---- prep + CSR build ----
    prep_kernel<<<1980, 256, 0, stream>>>(x, W1_rel, W1_root, W2_rel, W2_root,
                                          Wmu_rel, Wls_rel, Wmu_root, Wls_root,
                                          ax, xq, B1t, B2t, B3t, bcursor);
    partition_kernel<<<PBLK, 256, 0, stream>>>(src, dst, bcursor, pairbuf);
    fill_bucket_kernel<<<NBUCK, 256, 0, stream>>>(pairbuf, bcursor, row_beg, row_end, dinv, eidx);

    // ---- layer 1 + layer 2 (fused GEMMs, h1 lives in LDS) ----
    gather1_kernel<<<1563, 256, 0, stream>>>(row_beg, row_end, eidx, dinv, xq, ax);
    g12_kernel<<<782, 256, 0, stream>>>(ax, B1t, B2t, b1, t2, r2);

    // ---- layer-2 aggregation + layer-3 transform (fused) ----
    g2g3_kernel<<<3125, 256, 0, stream>>>(t2, r2, row_beg, row_end, eidx, dinv, b2, B3t, tml, rml);

    // ---- mu / logstd final aggregation ----
    gather3_kernel<<<782, 256, 0, stream>>>(tml, rml, row_beg, row_end, eidx, dinv, bmu, bls, out);
}

// Round 15
// 218.679 us; speedup vs baseline: 1.0173x; 1.0173x over previous
//
#include <hip/hip_runtime.h>
#include <hip/hip_fp8.h>

#define N_NODES 50000
#define N_EDGES 800000
#define NBUCK 196       // ceil(50000/256) buckets of 256 nodes
#define PBLK 391        // ceil(800000/2048) partition blocks
#define CAP 5120        // bucket window capacity

typedef unsigned short ushort_t;
typedef unsigned char uchar_t;
typedef short short8 __attribute__((ext_vector_type(8)));
typedef float floatx4 __attribute__((ext_vector_type(4)));

__device__ __forceinline__ float bf2f(ushort_t u) {
    unsigned v = ((unsigned)u) << 16;
    return __builtin_bit_cast(float, v);
}
__device__ __forceinline__ ushort_t f2bf(float f) {
    unsigned u = __builtin_bit_cast(unsigned, f);
    unsigned r = (u + 0x7FFFu + ((u >> 16) & 1u)) >> 16;  // RNE
    return (ushort_t)r;
}
__device__ __forceinline__ uchar_t f2fp8(float f) {
    __hip_fp8_e4m3 t(f);
    return (uchar_t)t.__x;
}
__device__ __forceinline__ float fp82f(uchar_t u) {
    __hip_fp8_e4m3 t;
    t.__x = (__hip_fp8_storage_t)u;
    return (float)t;
}
__device__ __forceinline__ float4 ld4(const float* p) { return *(const float4*)p; }

// ---------------- prep: cvt_x (bf16 + fp8) + cvt_w + bucket cursor init ----------------
__global__ __launch_bounds__(256) void prep_kernel(
    const float* __restrict__ x,
    const float* __restrict__ W1_rel, const float* __restrict__ W1_root,
    const float* __restrict__ W2_rel, const float* __restrict__ W2_root,
    const float* __restrict__ Wmu_rel, const float* __restrict__ Wls_rel,
    const float* __restrict__ Wmu_root, const float* __restrict__ Wls_root,
    ushort_t* __restrict__ ax, uchar_t* __restrict__ xq,
    ushort_t* __restrict__ B1t, ushort_t* __restrict__ B2t, ushort_t* __restrict__ B3t,
    int* __restrict__ bcursor) {
    int idx = blockIdx.x * blockDim.x + threadIdx.x;
    if (idx < 400000) {                       // ax[n,64:128] = bf16(x); xq[n,:] = fp8(x)
        int n = idx >> 3, c = (idx & 7) * 8;
        float4 v0 = ld4(x + (size_t)n * 64 + c);
        float4 v1 = ld4(x + (size_t)n * 64 + c + 4);
        float vv[8] = {v0.x, v0.y, v0.z, v0.w, v1.x, v1.y, v1.z, v1.w};
        short8 o;
        unsigned q0 = 0, q1 = 0;
        #pragma unroll
        for (int i = 0; i < 4; ++i) {
            o[i] = f2bf(vv[i]);
            o[4 + i] = f2bf(vv[4 + i]);
            q0 |= ((unsigned)f2fp8(vv[i])) << (8 * i);
            q1 |= ((unsigned)f2fp8(vv[4 + i])) << (8 * i);
        }
        *(short8*)(ax + (size_t)n * 128 + 64 + c) = o;
        uint2 q = {q0, q1};
        *(uint2*)(xq + (size_t)n * 64 + c) = q;
    } else if (idx < 506496) {                // transposed bf16 weights
        int j = idx - 400000;
        if (j < 32768) {
            int n = j >> 7, k = j & 127;
            float v = (k < 64) ? W1_rel[k * 256 + n] : W1_root[(k - 64) * 256 + n];
            B1t[j] = f2bf(v);
        } else if (j < 98304) {
            int jj = j - 32768;
            int n = jj >> 8, k = jj & 255;
            float v = (n < 128) ? W2_rel[k * 128 + n] : W2_root[k * 128 + (n - 128)];
            B2t[jj] = f2bf(v);
        } else {
            int jj = j - 98304;
            int n = jj >> 7, k = jj & 127;
            const float* W = (n < 16) ? Wmu_rel : (n < 32) ? Wls_rel : (n < 48) ? Wmu_root : Wls_root;
            B3t[jj] = f2bf(W[k * 16 + (n & 15)]);
        }
    } else if (idx < 506496 + NBUCK) {
        int b = idx - 506496;
        bcursor[b] = b * CAP;
    }
}

// ---------------- single-pass partition into fixed bucket windows ----------------
__global__ __launch_bounds__(256) void partition_kernel(
    const int* __restrict__ src, const int* __restrict__ dst,
    int* __restrict__ bcursor, unsigned* __restrict__ pairbuf) {
    __shared__ int h[NBUCK];
    __shared__ int cur[NBUCK];
    const int tid = threadIdx.x;
    for (int i = tid; i < NBUCK; i += 256) h[i] = 0;
    __syncthreads();
    const int base = blockIdx.x * 2048;
    int d[8];
    #pragma unroll
    for (int j = 0; j < 8; ++j) {
        int e = base + j * 256 + tid;
        if (e < N_EDGES) { d[j] = dst[e]; atomicAdd(&h[d[j] >> 8], 1); }
        else d[j] = -1;
    }
    __syncthreads();
    for (int i = tid; i < NBUCK; i += 256) {
        int c = h[i];
        cur[i] = c ? atomicAdd(&bcursor[i], c) : 0;
    }
    __syncthreads();
    #pragma unroll
    for (int j = 0; j < 8; ++j) {
        int e = base + j * 256 + tid;
        if (e < N_EDGES) {
            int dd = d[j];
            int slot = atomicAdd(&cur[dd >> 8], 1);
            pairbuf[slot] = (unsigned)src[e] | ((unsigned)(dd & 255) << 16);
        }
    }
}

// per-bucket: node histogram + scan -> row_beg/row_end/dinv; LDS-cursor fill of 16-bit eidx
__global__ __launch_bounds__(256) void fill_bucket_kernel(
    const unsigned* __restrict__ pairbuf, const int* __restrict__ bcursor,
    int* __restrict__ row_beg, int* __restrict__ row_end,
    float* __restrict__ dinv, ushort_t* __restrict__ eidx) {
    __shared__ int h[256];
    __shared__ int sm[256];
    __shared__ int cur[256];
    const int b = blockIdx.x, tid = threadIdx.x;
    const int beg = b * CAP, end = bcursor[b];
    h[tid] = 0;
    __syncthreads();
    for (int i = beg + tid; i < end; i += 256)
        atomicAdd(&h[pairbuf[i] >> 16], 1);
    __syncthreads();
    int c = h[tid];
    sm[tid] = c;
    __syncthreads();
    #pragma unroll
    for (int off = 1; off < 256; off <<= 1) {
        int t = (tid >= off) ? sm[tid - off] : 0;
        __syncthreads();
        sm[tid] += t;
        __syncthreads();
    }
    int exc = beg + sm[tid] - c;
    int node = b * 256 + tid;
    if (node < N_NODES) {
        row_beg[node] = exc;
        row_end[node] = exc + c;
        dinv[node] = c > 0 ? 1.0f / (float)c : 0.0f;
    }
    cur[tid] = exc;
    __syncthreads();
    for (int i = beg + tid; i < end; i += 256) {
        unsigned v = pairbuf[i];
        int slot = atomicAdd(&cur[v >> 16], 1);
        eidx[slot] = (ushort_t)(v & 0xFFFFu);
    }
}

// ---------------- gather 1: ax[:, 0:64] = mean-gather of xq (fp8) ----------------
__global__ __launch_bounds__(256) void gather1_kernel(
    const int* __restrict__ row_beg, const int* __restrict__ row_end,
    const ushort_t* __restrict__ eidx, const float* __restrict__ dinv,
    const uchar_t* __restrict__ xq, ushort_t* __restrict__ ax) {
    const int lane = threadIdx.x & 7;
    const int nl = threadIdx.x >> 3;
    const int n = blockIdx.x * 32 + nl;
    if (n >= N_NODES) return;
    const int beg = row_beg[n], end = row_end[n];
    float a0[8] = {}, a1[8] = {}, a2[8] = {}, a3[8] = {};
    int j = beg;
    for (; j + 3 < end; j += 4) {
        uint2 v0 = *(const uint2*)(xq + (size_t)eidx[j] * 64 + lane * 8);
        uint2 v1 = *(const uint2*)(xq + (size_t)eidx[j + 1] * 64 + lane * 8);
        uint2 v2 = *(const uint2*)(xq + (size_t)eidx[j + 2] * 64 + lane * 8);
        uint2 v3 = *(const uint2*)(xq + (size_t)eidx[j + 3] * 64 + lane * 8);
        #pragma unroll
        for (int i = 0; i < 4; ++i) {
            a0[i]     += fp82f((uchar_t)(v0.x >> (8 * i)));
            a0[4 + i] += fp82f((uchar_t)(v0.y >> (8 * i)));
            a1[i]     += fp82f((uchar_t)(v1.x >> (8 * i)));
            a1[4 + i] += fp82f((uchar_t)(v1.y >> (8 * i)));
            a2[i]     += fp82f((uchar_t)(v2.x >> (8 * i)));
            a2[4 + i] += fp82f((uchar_t)(v2.y >> (8 * i)));
            a3[i]     += fp82f((uchar_t)(v3.x >> (8 * i)));
            a3[4 + i] += fp82f((uchar_t)(v3.y >> (8 * i)));
        }
    }
    for (; j < end; ++j) {
        uint2 v0 = *(const uint2*)(xq + (size_t)eidx[j] * 64 + lane * 8);
        #pragma unroll
        for (int i = 0; i < 4; ++i) {
            a0[i]     += fp82f((uchar_t)(v0.x >> (8 * i)));
            a0[4 + i] += fp82f((uchar_t)(v0.y >> (8 * i)));
        }
    }
    float d = dinv[n];
    short8 o;
    #pragma unroll
    for (int i = 0; i < 8; ++i) o[i] = f2bf(((a0[i] + a1[i]) + (a2[i] + a3[i])) * d);
    *(short8*)(ax + (size_t)n * 128 + lane * 8) = o;
}

// ---------------- gemm1: h1 = relu(ax @ B1t + b1), K=128, N=256, ny loop ----------------
__global__ __launch_bounds__(256) void gemm1_mfma(
    const ushort_t* __restrict__ A, const ushort_t* __restrict__ Bt,
    const float* __restrict__ b1, ushort_t* __restrict__ h1) {
    constexpr int K = 128, KP = K + 8;
    __shared__ ushort_t Bs[64 * KP];
    const int tid = threadIdx.x;
    const int w = tid >> 6, lane = tid & 63;
    const int ln = lane & 15, quad = lane >> 4;
    const int rowbase = blockIdx.x * 64 + w * 16;
    int r = rowbase + ln; if (r > N_NODES - 1) r = N_NODES - 1;
    short8 a[4];
    #pragma unroll
    for (int s = 0; s < 4; ++s)
        a[s] = *(const short8*)(A + (size_t)r * K + s * 32 + quad * 8);
    const int r0 = rowbase + quad * 4;
    for (int ny = 0; ny < 4; ++ny) {
        __syncthreads();
        for (int i = tid; i < 64 * 16; i += 256) {
            int row = i >> 4, off = (i & 15) * 8;
            *(short8*)(Bs + row * KP + off) = *(const short8*)(Bt + (size_t)(ny * 64 + row) * K + off);
        }
        __syncthreads();
        floatx4 acc[4] = {};
        #pragma unroll
        for (int f = 0; f < 4; ++f) {
            const ushort_t* bp = Bs + (f * 16 + ln) * KP + quad * 8;
            #pragma unroll
            for (int s = 0; s < 4; ++s) {
                short8 b = *(const short8*)(bp + s * 32);
                acc[f] = __builtin_amdgcn_mfma_f32_16x16x32_bf16(a[s], b, acc[f], 0, 0, 0);
            }
        }
        #pragma unroll
        for (int f = 0; f < 4; ++f) {
            int n = ny * 64 + f * 16 + ln;
            float bias = b1[n];
            #pragma unroll
            for (int g = 0; g < 4; ++g) {
                int rr = r0 + g;
                if (rr >= N_NODES) continue;
                h1[(size_t)rr * 256 + n] = f2bf(fmaxf(acc[f][g] + bias, 0.0f));
            }
        }
    }
}

// ---------------- gemm2: [t2 fp8 | r2 bf16] = h1 @ [W2_rel | W2_root] ----------------
__global__ __launch_bounds__(256) void gemm2_mfma(
    const ushort_t* __restrict__ A, const ushort_t* __restrict__ Bt,
    uchar_t* __restrict__ t2, ushort_t* __restrict__ r2) {
    constexpr int K = 256, KP = K + 8;
    __shared__ ushort_t Bs[64 * KP];
    const int tid = threadIdx.x;
    const int w = tid >> 6, lane = tid & 63;
    const int ln = lane & 15, quad = lane >> 4;
    const int rowbase = blockIdx.x * 64 + w * 16;
    int r = rowbase + ln; if (r > N_NODES - 1) r = N_NODES - 1;
    short8 a[8];
    #pragma unroll
    for (int s = 0; s < 8; ++s)
        a[s] = *(const short8*)(A + (size_t)r * K + s * 32 + quad * 8);
    const int r0 = rowbase + quad * 4;
    for (int ny = 0; ny < 4; ++ny) {
        __syncthreads();
        for (int i = tid; i < 64 * 32; i += 256) {
            int row = i >> 5, off = (i & 31) * 8;
            *(short8*)(Bs + row * KP + off) = *(const short8*)(Bt + (size_t)(ny * 64 + row) * K + off);
        }
        __syncthreads();
        floatx4 acc[4] = {};
        #pragma unroll
        for (int f = 0; f < 4; ++f) {
            const ushort_t* bp = Bs + (f * 16 + ln) * KP + quad * 8;
            #pragma unroll
            for (int s = 0; s < 8; ++s) {
                short8 b = *(const short8*)(bp + s * 32);
                acc[f] = __builtin_amdgcn_mfma_f32_16x16x32_bf16(a[s], b, acc[f], 0, 0, 0);
            }
        }
        #pragma unroll
        for (int f = 0; f < 4; ++f) {
            int n = ny * 64 + f * 16 + ln;
            #pragma unroll
            for (int g = 0; g < 4; ++g) {
                int rr = r0 + g;
                if (rr >= N_NODES) continue;
                float v = acc[f][g];
                if (n < 128) t2[(size_t)rr * 128 + n] = f2fp8(v);
                else r2[(size_t)rr * 128 + (n - 128)] = f2bf(v);
            }
        }
    }
}

// ---------------- fused gather2 + combine + gemm3 (16 nodes/block, 16 threads/node) ----------------
__global__ __launch_bounds__(256) void g2g3_kernel(
    const uchar_t* __restrict__ t2, const ushort_t* __restrict__ r2,
    const int* __restrict__ row_beg, const int* __restrict__ row_end,
    const ushort_t* __restrict__ eidx, const float* __restrict__ dinv,
    const float* __restrict__ b2, const ushort_t* __restrict__ B3t,
    ushort_t* __restrict__ tml, float* __restrict__ rml) {
    constexpr int KP = 136;
    __shared__ ushort_t As[16 * KP];
    const int tid = threadIdx.x;
    const int nb = blockIdx.x * 16;   // 3125*16 = 50000 exact
    {
        const int nl = tid >> 4, lane = tid & 15;
        const int node = nb + nl;
        const int beg = row_beg[node], end = row_end[node];
        float a0[8] = {}, a1[8] = {}, a2[8] = {}, a3[8] = {};
        int j = beg;
        for (; j + 3 < end; j += 4) {
            uint2 v0 = *(const uint2*)(t2 + (size_t)eidx[j] * 128 + lane * 8);
            uint2 v1 = *(const uint2*)(t2 + (size_t)eidx[j + 1] * 128 + lane * 8);
            uint2 v2 = *(const uint2*)(t2 + (size_t)eidx[j + 2] * 128 + lane * 8);
            uint2 v3 = *(const uint2*)(t2 + (size_t)eidx[j + 3] * 128 + lane * 8);
            #pragma unroll
            for (int i = 0; i < 4; ++i) {
                a0[i]     += fp82f((uchar_t)(v0.x >> (8 * i)));
                a0[4 + i] += fp82f((uchar_t)(v0.y >> (8 * i)));
                a1[i]     += fp82f((uchar_t)(v1.x >> (8 * i)));
                a1[4 + i] += fp82f((uchar_t)(v1.y >> (8 * i)));
                a2[i]     += fp82f((uchar_t)(v2.x >> (8 * i)));
                a2[4 + i] += fp82f((uchar_t)(v2.y >> (8 * i)));
                a3[i]     += fp82f((uchar_t)(v3.x >> (8 * i)));
                a3[4 + i] += fp82f((uchar_t)(v3.y >> (8 * i)));
            }
        }
        for (; j < end; ++j) {
            uint2 v0 = *(const uint2*)(t2 + (size_t)eidx[j] * 128 + lane * 8);
            #pragma unroll
            for (int i = 0; i < 4; ++i) {
                a0[i]     += fp82f((uchar_t)(v0.x >> (8 * i)));
                a0[4 + i] += fp82f((uchar_t)(v0.y >> (8 * i)));
            }
        }
        float d = dinv[node];
        short8 rv = *(const short8*)(r2 + (size_t)node * 128 + lane * 8);
        float4 ba = ld4(b2 + lane * 8), bb = ld4(b2 + lane * 8 + 4);
        float bc[8] = {ba.x, ba.y, ba.z, ba.w, bb.x, bb.y, bb.z, bb.w};
        short8 o;
        #pragma unroll
        for (int i = 0; i < 8; ++i)
            o[i] = f2bf(fmaxf(((a0[i] + a1[i]) + (a2[i] + a3[i])) * d + bf2f((ushort_t)rv[i]) + bc[i], 0.0f));
        *(short8*)(As + nl * KP + lane * 8) = o;
    }
    __syncthreads();
    const int w = tid >> 6, lane64 = tid & 63;
    const int ln = lane64 & 15, quad = lane64 >> 4;
    short8 a[4];
    #pragma unroll
    for (int s = 0; s < 4; ++s)
        a[s] = *(const short8*)(As + ln * KP + s * 32 + quad * 8);
    floatx4 acc = {};
    const ushort_t* bp = B3t + (size_t)(w * 16 + ln) * 128 + quad * 8;
    #pragma unroll
    for (int s = 0; s < 4; ++s) {
        short8 b = *(const short8*)(bp + s * 32);
        acc = __builtin_amdgcn_mfma_f32_16x16x32_bf16(a[s], b, acc, 0, 0, 0);
    }
    const int r0 = nb + quad * 4;
    const int ncol = w * 16 + ln;
    #pragma unroll
    for (int g = 0; g < 4; ++g) {
        int rr = r0 + g;
        float v = acc[g];
        if (ncol < 32) tml[(size_t)rr * 32 + ncol] = f2bf(v);
        else rml[(size_t)rr * 32 + (ncol - 32)] = v;
    }
}

// ---------------- gather 3 (fused combine + split write, 4-edge unroll) ----------------
__global__ __launch_bounds__(256) void gather3_kernel(
    const ushort_t* __restrict__ tml, const float* __restrict__ rml,
    const int* __restrict__ row_beg, const int* __restrict__ row_end,
    const ushort_t* __restrict__ eidx, const float* __restrict__ dinv,
    const float* __restrict__ bmu, const float* __restrict__ bls,
    float* __restrict__ out) {
    const int lane = threadIdx.x & 3;
    const int nl = threadIdx.x >> 2;
    const int n = blockIdx.x * 64 + nl;
    if (n >= N_NODES) return;
    const int beg = row_beg[n], end = row_end[n];
    float a0[8] = {}, a1[8] = {}, a2[8] = {}, a3[8] = {};
    int j = beg;
    for (; j + 3 < end; j += 4) {
        short8 v0 = *(const short8*)(tml + (size_t)eidx[j] * 32 + lane * 8);
        short8 v1 = *(const short8*)(tml + (size_t)eidx[j + 1] * 32 + lane * 8);
        short8 v2 = *(const short8*)(tml + (size_t)eidx[j + 2] * 32 + lane * 8);
        short8 v3 = *(const short8*)(tml + (size_t)eidx[j + 3] * 32 + lane * 8);
        #pragma unroll
        for (int i = 0; i < 8; ++i) {
            a0[i] += bf2f((ushort_t)v0[i]); a1[i] += bf2f((ushort_t)v1[i]);
            a2[i] += bf2f((ushort_t)v2[i]); a3[i] += bf2f((ushort_t)v3[i]);
        }
    }
    for (; j < end; ++j) {
        short8 v0 = *(const short8*)(tml + (size_t)eidx[j] * 32 + lane * 8);
        #pragma unroll
        for (int i = 0; i < 8; ++i) a0[i] += bf2f((ushort_t)v0[i]);
    }
    float d = dinv[n];
    const float* bias = (lane < 2) ? (bmu + lane * 8) : (bls + (lane - 2) * 8);
    float4 ra = ld4(rml + (size_t)n * 32 + lane * 8);
    float4 rb = ld4(rml + (size_t)n * 32 + lane * 8 + 4);
    float4 ba = ld4(bias);
    float4 bb = ld4(bias + 4);
    float rr[8] = {ra.x, ra.y, ra.z, ra.w, rb.x, rb.y, rb.z, rb.w};
    float bc[8] = {ba.x, ba.y, ba.z, ba.w, bb.x, bb.y, bb.z, bb.w};
    float res[8];
    #pragma unroll
    for (int i = 0; i < 8; ++i) res[i] = ((a0[i] + a1[i]) + (a2[i] + a3[i])) * d + rr[i] + bc[i];
    float* base = (lane < 2) ? (out + (size_t)n * 16 + lane * 8)
                             : (out + 800000u + (size_t)n * 16 + (lane - 2) * 8);
    *(float4*)(base) = make_float4(res[0], res[1], res[2], res[3]);
    *(float4*)(base + 4) = make_float4(res[4], res[5], res[6], res[7]);
}

extern "C" void kernel_launch(void* const* d_in, const int* in_sizes, int n_in,
                              void* d_out, int out_size, void* d_ws, size_t ws_size,
                              hipStream_t stream) {
    const float* x       = (const float*)d_in[0];
    const float* W1_rel  = (const float*)d_in[1];
    const float* b1      = (const float*)d_in[2];
    const float* W1_root = (const float*)d_in[3];
    const float* W2_rel  = (const float*)d_in[4];
    const float* b2      = (const float*)d_in[5];
    const float* W2_root = (const float*)d_in[6];
    const float* Wmu_rel = (const float*)d_in[7];
    const float* bmu     = (const float*)d_in[8];
    const float* Wmu_root= (const float*)d_in[9];
    const float* Wls_rel = (const float*)d_in[10];
    const float* bls     = (const float*)d_in[11];
    const float* Wls_root= (const float*)d_in[12];
    const int*   ei      = (const int*)d_in[13];
    const int* src = ei;
    const int* dst = ei + N_EDGES;

    // ---- workspace layout ----
    int*      bcursor = (int*)d_ws;                      //       256
    int*      row_beg = bcursor + 256;                   //    50,048
    int*      row_end = row_beg + 50048;                 //    50,048
    unsigned* pairbuf = (unsigned*)(row_end + 50048);    // 1,003,520
    ushort_t* eidx    = (ushort_t*)(pairbuf + 1003520);  // 1,003,520 ush
    float*    dinv    = (float*)(eidx + 1003520);        //    50,000
    ushort_t* ax   = (ushort_t*)(dinv + 50000);          //  6,400,000  [N,128]: [agg | x]
    ushort_t* h1   = ax + 6400000;                       // 12,800,000  [N,256] bf16
    uchar_t*  t2   = (uchar_t*)(h1 + 12800000);          //  6,400,000 B [N,128] fp8
    uchar_t*  xq   = t2 + 6400000;                       //  3,200,000 B [N,64] fp8
    ushort_t* r2   = (ushort_t*)(xq + 3200000);          //  6,400,000  [N,128] bf16
    ushort_t* tml  = r2 + 6400000;                       //  1,600,000  [N,32]  bf16
    ushort_t* B1t  = tml + 1600000;                      //     32,768
    ushort_t* B2t  = B1t + 32768;                        //     65,536
    ushort_t* B3t  = B2t + 65536;                        //      8,192
    float* rml     = (float*)(B3t + 8192);               //  1,600,000  [N,32] f32
    float* out     = (float*)d_out;

    // ---- prep + CSR build ----
    prep_kernel<<<1980, 256, 0, stream>>>(x, W1_rel, W1_root, W2_rel, W2_root,
                                          Wmu_rel, Wls_rel, Wmu_root, Wls_root,
                                          ax, xq, B1t, B2t, B3t, bcursor);
    partition_kernel<<<PBLK, 256, 0, stream>>>(src, dst, bcursor, pairbuf);
    fill_bucket_kernel<<<NBUCK, 256, 0, stream>>>(pairbuf, bcursor, row_beg, row_end, dinv, eidx);

    // ---- layer 1 ----
    gather1_kernel<<<1563, 256, 0, stream>>>(row_beg, row_end, eidx, dinv, xq, ax);
    gemm1_mfma<<<782, 256, 0, stream>>>(ax, B1t, b1, h1);

    // ---- layer 2 + fused layer-3 transform ----
    gemm2_mfma<<<782, 256, 0, stream>>>(h1, B2t, t2, r2);
    g2g3_kernel<<<3125, 256, 0, stream>>>(t2, r2, row_beg, row_end, eidx, dinv, b2, B3t, tml, rml);

    // ---- mu / logstd final aggregation ----
    gather3_kernel<<<782, 256, 0, stream>>>(tml, rml, row_beg, row_end, eidx, dinv, bmu, bls, out);
}